// Round 3
// baseline (217355.396 us; speedup 1.0000x reference)
//
#include <hip/hip_runtime.h>
#include <hip/hip_bf16.h>

// B=32, T_ENC=512, steps TD=501, D_ENC=512, N_MEL=160, H=1024, 4H=4096
// aLSTM K = 256(pre)+512(ctx)+1024(ah) = 1792 ; dLSTM K = 512(ctx)+1024(ah)+1024(dh) = 2560
// ALL external I/O is fp32 (reference uses jnp.float32). Internal staging: bf16 weights.

typedef __hip_bfloat16 bf16;

__device__ __forceinline__ float b2f(bf16 x){ return __bfloat162float(x); }
__device__ __forceinline__ bf16 f2b(float x){ return __float2bfloat16(x); }
__device__ __forceinline__ float sig_s(float x){
  if (x > 30.f) return 1.f; if (x < -30.f) return 0.f;
  return 1.f/(1.f+__expf(-x)); }
__device__ __forceinline__ float tanh_s(float x){
  if (x > 15.f) return 1.f; if (x < -15.f) return -1.f;
  float e=__expf(2.f*x); return 1.f-2.f/(e+1.f); }

// ---------------- workspace layout ----------------
constexpr size_t S_MKT  = 32ull*128*512;   // 2,097,152 fp32
constexpr size_t S_CTX  = 32ull*512;
constexpr size_t S_H    = 32ull*1024;
constexpr size_t S_AW   = 32ull*512;
constexpr size_t S_GP   = 10ull*32*4096;   // 10 chunks of 256-K
constexpr size_t S_CNV  = 32ull*32*512;

constexpr size_t OFF_MKT  = 0;
constexpr size_t OFF_CTX  = OFF_MKT + S_MKT;   // zeroed state block start
constexpr size_t OFF_AH   = OFF_CTX + S_CTX;
constexpr size_t OFF_AC   = OFF_AH + S_H;
constexpr size_t OFF_DH   = OFF_AC + S_H;
constexpr size_t OFF_DC   = OFF_DH + S_H;
constexpr size_t OFF_AW   = OFF_DC + S_H;
constexpr size_t OFF_AWT  = OFF_AW + S_AW;
constexpr size_t STATE_LEN = S_CTX + 4*S_H + 2*S_AW;  // 180,224
constexpr size_t OFF_GP   = OFF_AWT + S_AW;
constexpr size_t OFF_CNV  = OFF_GP + S_GP;
constexpr size_t OFF_BIASA= OFF_CNV + S_CNV;
constexpr size_t OFF_BIASD= OFF_BIASA + 4096;
constexpr size_t OFF_CWF  = OFF_BIASD + 4096;   // conv_w 32*2*31=1984
constexpr size_t OFF_CBF  = OFF_CWF + 1984;
constexpr size_t OFF_WLF  = OFF_CBF + 32;       // wl 128*32
constexpr size_t OFF_BLF  = OFF_WLF + 4096;
constexpr size_t OFF_WAF  = OFF_BLF + 128;
constexpr size_t OFF_F32_END = OFF_WAF + 128;

constexpr size_t OFF_PRE2B_BYTES = ((OFF_F32_END*4 + 255)/256)*256;
constexpr size_t S_PRE2B = 501ull*32*256;                       // bf16
constexpr size_t OFF_WAT_BYTES = ((OFF_PRE2B_BYTES + S_PRE2B*2 + 255)/256)*256;
constexpr size_t S_WAT = 1792ull*4096;                          // bf16
constexpr size_t OFF_WDT_BYTES = OFF_WAT_BYTES + S_WAT*2;
constexpr size_t S_WDT = 2560ull*4096;                          // bf16
constexpr size_t WS_NEEDED = OFF_WDT_BYTES + S_WDT*2;           // ~60.4 MB

// output offsets (fp32 elements in d_out)
constexpr size_t OUT_MEL  = 0;
constexpr size_t OUT_GATE = 501ull*32*160;
constexpr size_t OUT_ATTN = OUT_GATE + 501ull*32;

// ---------------- prep kernels ----------------
__global__ void k_zero(float* __restrict__ p, int n){
  int i = blockIdx.x*256 + threadIdx.x;
  if (i < n) p[i] = 0.f;
}

__global__ void k_smalls(const float* __restrict__ cw, const float* __restrict__ cb,
                         const float* __restrict__ wl, const float* __restrict__ bl,
                         const float* __restrict__ wa,
                         float* __restrict__ cwf, float* __restrict__ cbf,
                         float* __restrict__ wlf, float* __restrict__ blf,
                         float* __restrict__ waf){
  int i = blockIdx.x*256 + threadIdx.x;
  if (i < 1984) cwf[i] = cw[i];
  if (i < 32)   cbf[i] = cb[i];
  if (i < 4096) wlf[i] = wl[i];
  if (i < 128)  blf[i] = bl[i];
  if (i < 128)  waf[i] = wa[i];
}

__global__ void k_bias(const float* __restrict__ b1, const float* __restrict__ b2,
                       float* __restrict__ out){
  int i = blockIdx.x*256 + threadIdx.x;
  if (i < 4096) out[i] = b1[i] + b2[i];
}

// dst[(koff + c)*4096 + r] = bf16(src[r*C + c])   (src fp32, 4096 rows x C cols)
__global__ __launch_bounds__(256) void k_trans(const float* __restrict__ src, int C,
                                               bf16* __restrict__ dst, int koff){
  __shared__ bf16 tile[64][65];
  int r0 = blockIdx.x*64, c0 = blockIdx.y*64;
  int tx = threadIdx.x & 63, ty = threadIdx.x >> 6;
  for (int rr = ty; rr < 64; rr += 4)
    tile[rr][tx] = f2b(src[(size_t)(r0+rr)*C + c0 + tx]);
  __syncthreads();
  for (int rr = ty; rr < 64; rr += 4)
    dst[(size_t)(koff + c0 + rr)*4096 + r0 + tx] = tile[tx][rr];
}

// prenet -> pre2b[tt][b][j] (bf16)
__global__ __launch_bounds__(256) void k_prenet(const float* __restrict__ mels,
    const float* __restrict__ w1, const float* __restrict__ b1,
    const float* __restrict__ w2, const float* __restrict__ b2,
    bf16* __restrict__ pre2){
  __shared__ float mel[160];
  __shared__ float x1[256];
  int b = blockIdx.x, tid = threadIdx.x;
  for (int ti = 0; ti < 8; ++ti){
    int tt = blockIdx.y*8 + ti;
    if (tt >= 501) break;
    if (tid < 160) mel[tid] = (tt == 0) ? 0.f : mels[((size_t)b*500 + (tt-1))*160 + tid];
    __syncthreads();
    float a = b1[tid];
    for (int k = 0; k < 160; ++k) a += mel[k]*w1[tid*160 + k];
    x1[tid] = fmaxf(a, 0.f);
    __syncthreads();
    float a2 = b2[tid];
    for (int k = 0; k < 256; ++k) a2 += x1[k]*w2[tid*256 + k];
    pre2[((size_t)tt*32 + b)*256 + tid] = f2b(fmaxf(a2, 0.f));
    __syncthreads();
  }
}

// mkT[b][c][t] = dot(enc[b][t][:], wk[c][:]) + bk[c]   (fp32)
__global__ __launch_bounds__(128) void k_memkeys(const float* __restrict__ enc,
    const float* __restrict__ wk, const float* __restrict__ bk, float* __restrict__ mkT){
  __shared__ float er[512];
  int b = blockIdx.x, tid = threadIdx.x;
  for (int i = 0; i < 8; ++i){
    int t = blockIdx.y*8 + i;
    const float* e = enc + ((size_t)b*512 + t)*512;
    for (int k = tid; k < 512; k += 128) er[k] = e[k];
    __syncthreads();
    float a = bk[tid];
    for (int k = 0; k < 512; ++k) a += er[k]*wk[tid*512 + k];
    mkT[((size_t)b*128 + tid)*512 + t] = a;
    __syncthreads();
  }
}

// ---------------- per-step kernels ----------------
// skinny GEMM, K-chunks of 256 (all source boundaries 256-aligned).
// grid (16 j-tiles, nchunks), block 512 = 256 j x 2 b-halves. Gp[chunk][b][j].
__global__ __launch_bounds__(512) void k_gates(const bf16* __restrict__ Wt,
    const bf16* __restrict__ x0b, const float* __restrict__ x0f, int l0,
    const float* __restrict__ x1, int l1,
    const float* __restrict__ x2, int l2,
    float* __restrict__ Gp){
  int j = blockIdx.x*256 + (threadIdx.x & 255);
  int half = __builtin_amdgcn_readfirstlane(threadIdx.x >> 8);
  int k0 = blockIdx.y*256;
  const float* xf = x0f; const bf16* xb = x0b; int stride, kl0;
  bool useB;
  if (k0 < l0){ stride = l0; kl0 = k0; useB = (x0b != nullptr); }
  else if (k0 < l0 + l1){ xf = x1; stride = l1; kl0 = k0 - l0; useB = false; }
  else { xf = x2; stride = l2; kl0 = k0 - l0 - l1; useB = false; }
  float acc[16];
  #pragma unroll
  for (int i = 0; i < 16; ++i) acc[i] = 0.f;
  for (int kk = 0; kk < 256; ++kk){
    float w = b2f(Wt[(size_t)(k0+kk)*4096 + j]);
    int kl = kl0 + kk;
    if (useB){
      #pragma unroll
      for (int bb = 0; bb < 16; ++bb)
        acc[bb] = fmaf(b2f(xb[(size_t)(half*16 + bb)*stride + kl]), w, acc[bb]);
    } else {
      #pragma unroll
      for (int bb = 0; bb < 16; ++bb)
        acc[bb] = fmaf(xf[(size_t)(half*16 + bb)*stride + kl], w, acc[bb]);
    }
  }
  size_t base = (size_t)blockIdx.y*(32*4096) + (size_t)(half*16)*4096 + j;
  #pragma unroll
  for (int bb = 0; bb < 16; ++bb) Gp[base + (size_t)bb*4096] = acc[bb];
}

// LSTM cell: reduce chunk partials + nonlinearity. grid 128, block 256.
__global__ __launch_bounds__(256) void k_cell(const float* __restrict__ Gp, int nch,
    const float* __restrict__ bias, float* __restrict__ h, float* __restrict__ c){
  int idx = blockIdx.x*256 + threadIdx.x;
  int b = idx >> 10, u = idx & 1023;
  float gi = bias[u], gf = bias[1024+u], gg = bias[2048+u], go = bias[3072+u];
  for (int ci = 0; ci < nch; ++ci){
    const float* p = Gp + (size_t)ci*(32*4096) + (size_t)b*4096 + u;
    gi += p[0]; gf += p[1024]; gg += p[2048]; go += p[3072];
  }
  float cp = c[idx];
  float cn = sig_s(gf)*cp + sig_s(gi)*tanh_s(gg);
  h[idx] = sig_s(go)*tanh_s(cn);
  c[idx] = cn;
}

// location conv: cnv[b][o][t]
__global__ __launch_bounds__(256) void k_conv(const float* __restrict__ aw,
    const float* __restrict__ awt, const float* __restrict__ cwf,
    const float* __restrict__ cbf, float* __restrict__ cnv){
  __shared__ float s0[158], s1[158];
  int b = blockIdx.x;
  int t = threadIdx.x & 127;
  int oh = __builtin_amdgcn_readfirstlane(threadIdx.x >> 7);
  int tbase = blockIdx.y*128;
  for (int i = threadIdx.x; i < 316; i += 256){
    int ch = i / 158, p = i - ch*158;
    int pos = tbase + p - 15;
    float v = (pos >= 0 && pos < 512) ? (ch ? awt[b*512 + pos] : aw[b*512 + pos]) : 0.f;
    if (ch) s1[p] = v; else s0[p] = v;
  }
  __syncthreads();
  float acc[16];
  #pragma unroll
  for (int o = 0; o < 16; ++o) acc[o] = 0.f;
  for (int k = 0; k < 31; ++k){
    float v0 = s0[t+k], v1 = s1[t+k];
    #pragma unroll
    for (int o = 0; o < 16; ++o){
      int oo = oh*16 + o;
      acc[o] += cwf[oo*62 + k]*v0 + cwf[oo*62 + 31 + k]*v1;
    }
  }
  int tg = tbase + t;
  #pragma unroll
  for (int o = 0; o < 16; ++o){
    int oo = oh*16 + o;
    cnv[((size_t)b*32 + oo)*512 + tg] = acc[o] + cbf[oo];
  }
}

// attention with fused location projection. one block per b, 512 threads.
__global__ __launch_bounds__(512) void k_attn(
    const float* __restrict__ ah, const float* __restrict__ wq, const float* __restrict__ bq,
    const float* __restrict__ mkT, const float* __restrict__ cnv,
    const float* __restrict__ wlf, const float* __restrict__ blf,
    const float* __restrict__ waf, const float* __restrict__ ba,
    const unsigned char* __restrict__ mask, const float* __restrict__ enc,
    float* __restrict__ aw, float* __restrict__ awt, float* __restrict__ ctx,
    float* __restrict__ attn_out){
  __shared__ float wlS[4096];
  __shared__ float sq[128];
  __shared__ float qp[4][128];
  __shared__ float red[8];
  __shared__ float saw[512];
  int b = blockIdx.x, tid = threadIdx.x;
  int lane = tid & 63, wv = tid >> 6;
  for (int i = tid; i < 4096; i += 512) wlS[i] = wlf[i];
  // query = ah[b] @ wq.T + bq   (+ bl folded in)
  {
    int c = tid & 127, kq = tid >> 7;
    const float* ahb = ah + (size_t)b*1024;
    float p = 0.f;
    for (int k = kq*256; k < kq*256 + 256; ++k) p += ahb[k]*wq[(size_t)c*1024 + k];
    qp[kq][c] = p;
  }
  __syncthreads();
  if (tid < 128) sq[tid] = qp[0][tid] + qp[1][tid] + qp[2][tid] + qp[3][tid]
                         + bq[tid] + blf[tid];
  __syncthreads();
  // e[t] = sum_c wa[c]*tanh(sq[c] + mk[b][c][t] + sum_o wl[c][o]*cnv[b][o][t]) + ba
  float e;
  {
    float rv[32];
    const float* cb = cnv + (size_t)b*32*512 + tid;
    #pragma unroll
    for (int o = 0; o < 32; ++o) rv[o] = cb[(size_t)o*512];
    const float* mk = mkT + (size_t)b*128*512;
    float acc = 0.f;
    for (int c = 0; c < 128; ++c){
      float lc = 0.f;
      #pragma unroll
      for (int o = 0; o < 32; ++o) lc += wlS[c*32 + o]*rv[o];
      float s = sq[c] + mk[(size_t)c*512 + tid] + lc;
      acc += tanh_s(s)*waf[c];
    }
    e = acc + ba[0];
    if (mask[b*512 + tid]) e = -1e30f;
  }
  // softmax over t
  float m = e;
  #pragma unroll
  for (int off = 32; off > 0; off >>= 1) m = fmaxf(m, __shfl_down(m, off, 64));
  if (lane == 0) red[wv] = m;
  __syncthreads();
  if (tid == 0){ float mm = red[0]; for (int i = 1; i < 8; ++i) mm = fmaxf(mm, red[i]); red[0] = mm; }
  __syncthreads();
  float M = red[0];
  __syncthreads();
  float p = __expf(e - M);
  float s = p;
  #pragma unroll
  for (int off = 32; off > 0; off >>= 1) s += __shfl_down(s, off, 64);
  if (lane == 0) red[wv] = s;
  __syncthreads();
  if (tid == 0){ float ss = 0.f; for (int i = 0; i < 8; ++i) ss += red[i]; red[0] = ss; }
  __syncthreads();
  float av = p / red[0];
  aw[b*512 + tid] = av;
  awt[b*512 + tid] += av;
  attn_out[(size_t)b*512 + tid] = av;
  saw[tid] = av;
  __syncthreads();
  // ctx[b][d] = sum_t aw[t]*enc[b][t][d]
  {
    const float* eb = enc + (size_t)b*512*512 + tid;
    float acc = 0.f;
    for (int tt = 0; tt < 512; ++tt) acc += saw[tt]*eb[(size_t)tt*512];
    ctx[b*512 + tid] = acc;
  }
}

// output projection: 161 outputs per b (160 mel + 1 gate), one wave per output
__global__ __launch_bounds__(256) void k_out(
    const float* __restrict__ dh, const float* __restrict__ ctx,
    const float* __restrict__ wm, const float* __restrict__ bm,
    const float* __restrict__ wg, const float* __restrict__ bg,
    float* __restrict__ mel_out, float* __restrict__ gate_out){
  int wid = blockIdx.x*4 + (threadIdx.x >> 6);
  if (wid >= 32*161) return;
  int lane = threadIdx.x & 63;
  int b = wid / 161, j = wid - b*161;
  const float* wrow = (j < 160) ? (wm + (size_t)j*1536) : wg;
  const float* dhb = dh + (size_t)b*1024;
  const float* cxb = ctx + (size_t)b*512;
  float acc = 0.f;
  for (int k = lane; k < 1536; k += 64){
    float x = (k < 1024) ? dhb[k] : cxb[k - 1024];
    acc += x*wrow[k];
  }
  #pragma unroll
  for (int off = 32; off > 0; off >>= 1) acc += __shfl_down(acc, off, 64);
  if (lane == 0){
    if (j < 160) mel_out[b*160 + j] = acc + bm[j];
    else gate_out[b] = acc + bg[0];
  }
}

// ---------------- launch ----------------
extern "C" void kernel_launch(void* const* d_in, const int* in_sizes, int n_in,
                              void* d_out, int out_size, void* d_ws, size_t ws_size,
                              hipStream_t stream){
  if (ws_size < WS_NEEDED) return;  // diagnostic: absmax==max|ref| => ws too small

  const float* enc    = (const float*)d_in[0];
  const float* mels   = (const float*)d_in[1];
  const unsigned char* mask = (const unsigned char*)d_in[2];
  const float* w_pre1 = (const float*)d_in[3];
  const float* b_pre1 = (const float*)d_in[4];
  const float* w_pre2 = (const float*)d_in[5];
  const float* b_pre2 = (const float*)d_in[6];
  const float* wih_a  = (const float*)d_in[7];
  const float* whh_a  = (const float*)d_in[8];
  const float* bih_a  = (const float*)d_in[9];
  const float* bhh_a  = (const float*)d_in[10];
  const float* wq     = (const float*)d_in[11];
  const float* bq     = (const float*)d_in[12];
  const float* wk     = (const float*)d_in[13];
  const float* bk     = (const float*)d_in[14];
  const float* conv_w = (const float*)d_in[15];
  const float* conv_b = (const float*)d_in[16];
  const float* wl     = (const float*)d_in[17];
  const float* bl     = (const float*)d_in[18];
  const float* wa     = (const float*)d_in[19];
  const float* ba     = (const float*)d_in[20];
  const float* wih_d  = (const float*)d_in[21];
  const float* whh_d  = (const float*)d_in[22];
  const float* bih_d  = (const float*)d_in[23];
  const float* bhh_d  = (const float*)d_in[24];
  const float* wm     = (const float*)d_in[25];
  const float* bm     = (const float*)d_in[26];
  const float* wg     = (const float*)d_in[27];
  const float* bg     = (const float*)d_in[28];

  float* W = (float*)d_ws;
  float* mkT  = W + OFF_MKT;
  float* ctx  = W + OFF_CTX;
  float* ah   = W + OFF_AH;
  float* ac   = W + OFF_AC;
  float* dh   = W + OFF_DH;
  float* dc   = W + OFF_DC;
  float* aw   = W + OFF_AW;
  float* awt  = W + OFF_AWT;
  float* Gp   = W + OFF_GP;
  float* cnv  = W + OFF_CNV;
  float* biasA= W + OFF_BIASA;
  float* biasD= W + OFF_BIASD;
  float* cwf  = W + OFF_CWF;
  float* cbf  = W + OFF_CBF;
  float* wlf  = W + OFF_WLF;
  float* blf  = W + OFF_BLF;
  float* waf  = W + OFF_WAF;
  bf16* pre2b = (bf16*)((char*)d_ws + OFF_PRE2B_BYTES);
  bf16* WaT   = (bf16*)((char*)d_ws + OFF_WAT_BYTES);
  bf16* WdT   = (bf16*)((char*)d_ws + OFF_WDT_BYTES);

  float* out    = (float*)d_out;
  float* melOut = out + OUT_MEL;
  float* gateOut= out + OUT_GATE;
  float* attnOut= out + OUT_ATTN;

  // ---- prep ----
  k_zero<<<(int)((STATE_LEN + 255)/256), 256, 0, stream>>>(ctx, (int)STATE_LEN);
  k_smalls<<<16, 256, 0, stream>>>(conv_w, conv_b, wl, bl, wa, cwf, cbf, wlf, blf, waf);
  k_bias<<<16, 256, 0, stream>>>(bih_a, bhh_a, biasA);
  k_bias<<<16, 256, 0, stream>>>(bih_d, bhh_d, biasD);
  k_trans<<<dim3(64, 12), 256, 0, stream>>>(wih_a, 768,  WaT, 0);
  k_trans<<<dim3(64, 16), 256, 0, stream>>>(whh_a, 1024, WaT, 768);
  k_trans<<<dim3(64, 24), 256, 0, stream>>>(wih_d, 1536, WdT, 0);
  k_trans<<<dim3(64, 16), 256, 0, stream>>>(whh_d, 1024, WdT, 1536);
  k_prenet<<<dim3(32, 63), 256, 0, stream>>>(mels, w_pre1, b_pre1, w_pre2, b_pre2, pre2b);
  k_memkeys<<<dim3(32, 64), 128, 0, stream>>>(enc, wk, bk, mkT);

  // ---- recurrence ----
  for (int t = 0; t < 501; ++t){
    k_gates<<<dim3(16, 7), 512, 0, stream>>>(WaT, pre2b + (size_t)t*32*256, nullptr, 256,
                                             ctx, 512, ah, 1024, Gp);
    k_cell<<<128, 256, 0, stream>>>(Gp, 7, biasA, ah, ac);
    k_conv<<<dim3(32, 4), 256, 0, stream>>>(aw, awt, cwf, cbf, cnv);
    k_attn<<<32, 512, 0, stream>>>(ah, wq, bq, mkT, cnv, wlf, blf, waf, ba, mask, enc,
                                   aw, awt, ctx, attnOut + (size_t)t*32*512);
    k_gates<<<dim3(16, 10), 512, 0, stream>>>(WdT, nullptr, ctx, 512,
                                              ah, 1024, dh, 1024, Gp);
    k_cell<<<128, 256, 0, stream>>>(Gp, 10, biasD, dh, dc);
    k_out<<<1288, 256, 0, stream>>>(dh, ctx, wm, bm, wg, bg,
                                    melOut + (size_t)t*32*160, gateOut + (size_t)t*32);
  }
}